// Round 3
// baseline (1306.936 us; speedup 1.0000x reference)
//
#include <hip/hip_runtime.h>

// ---------------------------------------------------------------------------
// MoE (b=4,n=2048,d=1024,dc=256,dff=4096,E=8,K=2,cap=2560). Pipeline:
//   probe -> cvt(x,cond->bf16) -> router(f32) -> bins ->
//   transpose weights(->bf16) -> GEMM1 (8-phase 256x256, gelu) ->
//   GEMM2 (8-phase 256x128) -> combine.
// 8-phase template v3: ONE-PHASE READ-AHEAD. ds_reads for phase p's MFMA are
// issued in phase p-1's open region; MID waits are counted lgkmcnt(<issued
// this phase>), so LDS execution overlaps the MFMA region (round-2 showed
// serialized phases: 1680 cyc vs 620 MFMA + 580 LDS content). Fragments are
// double-buffered (a[qm],b[qn] sets). Stages shift one phase earlier; counted
// vmcnt at p3/p7 close (VMW=2+SB). Full land/WAR ledger in the kernel header.
// ---------------------------------------------------------------------------

typedef unsigned short u16;
typedef unsigned int u32;
typedef __bf16 bf16x8 __attribute__((ext_vector_type(8)));
typedef float f32x4 __attribute__((ext_vector_type(4)));

constexpr int T_TOK = 8192;
constexpr int DIM   = 1024;
constexpr int DCOND = 256;
constexpr int DFF   = 4096;
constexpr int NEXP  = 8;
constexpr int CAP   = 2560;   // int(1.25 * 2 * 8192 / 8)

__device__ __forceinline__ float b2f(u16 u) {
    union { u32 u; float f; } v; v.u = (u32)u << 16; return v.f;
}
__device__ __forceinline__ u16 f2b(float f) {
    union { float f; u32 u; } v; v.f = f;
    u32 r = (v.u + 0x7fffu + ((v.u >> 16) & 1u)) >> 16;
    return (u16)r;
}
// Fast tanh-gelu: tanh(z) = 1 - 2/(exp(2z)+1). Matches tanhf to ~1e-6.
__device__ __forceinline__ float gelu_f(float x) {
    if (!(x == x)) x = 0.f;
    x = fminf(1e4f, fmaxf(-1e4f, x));
    float z = 0.7978845608028654f * (x + 0.044715f * x * x * x);
    float e = __expf(2.0f * z);
    float th = 1.0f - 2.0f / (e + 1.0f);
    return 0.5f * x * (1.0f + th);
}

// global -> LDS DMA, 16 B per lane; LDS dest is wave-uniform base + lane*16.
__device__ __forceinline__ void gload16(const u16* g, u16* l) {
    __builtin_amdgcn_global_load_lds(
        (const __attribute__((address_space(1))) void*)g,
        (__attribute__((address_space(3))) void*)l, 16, 0, 0);
}

// Inline-asm LDS read (opaque to the memory legalizer: no vmcnt(0) ordering
// vs the global_load_lds DMA). IMM: compile-time byte offset.
template <int IMM>
__device__ __forceinline__ bf16x8 dsr(u32 addr) {
    bf16x8 d;
    asm volatile("ds_read_b128 %0, %1 offset:%2" : "=v"(d) : "v"(addr), "n"(IMM));
    return d;
}
template <int N>
__device__ __forceinline__ void vmwait() {
    asm volatile("s_waitcnt vmcnt(%0)" :: "n"(N) : "memory");
}
template <int N>
__device__ __forceinline__ void lgkmw() {
    asm volatile("s_waitcnt lgkmcnt(%0)" :: "n"(N) : "memory");
}

// ---------------------------------------------------------------------------
// Dtype probe: flag=1 means inputs are float32.
// ---------------------------------------------------------------------------
__global__ void moe_probe(const u16* __restrict__ x, int* __restrict__ flag) {
    const int lane = threadIdx.x;   // 64 threads
    int cnt = 0;
    for (int i = lane; i < 4096; i += 64) {
        int e = (x[i] >> 7) & 0xFF;
        cnt += (e >= 0xC8);
    }
#pragma unroll
    for (int off = 32; off; off >>= 1) cnt += __shfl_xor(cnt, off, 64);
    if (lane == 0) flag[0] = (cnt > 8) ? 1 : 0;
}

// ---------------------------------------------------------------------------
// cvt: normalize a tensor to bf16 (straight copy if already bf16).
// ---------------------------------------------------------------------------
__global__ __launch_bounds__(256) void moe_cvt(
    const void* __restrict__ in, u16* __restrict__ out,
    const int* __restrict__ flag)
{
    const long long i = ((long long)blockIdx.x * 256 + threadIdx.x) * 8;
    if (flag[0]) {
        const float* s = (const float*)in + i;
        float4 a = *(const float4*)s;
        float4 b = *(const float4*)(s + 4);
        __align__(16) u16 t8[8];
        t8[0] = f2b(a.x); t8[1] = f2b(a.y); t8[2] = f2b(a.z); t8[3] = f2b(a.w);
        t8[4] = f2b(b.x); t8[5] = f2b(b.y); t8[6] = f2b(b.z); t8[7] = f2b(b.w);
        *(uint4*)(out + i) = *(const uint4*)t8;
    } else {
        *(uint4*)(out + i) = *(const uint4*)((const u16*)in + i);
    }
}

// ---------------------------------------------------------------------------
// Router: one wave per token, f32 logits (reads ORIGINAL x so top-k ties
// match the f32 reference), top-2 lower-index-wins, 2-way softmax weights.
// ---------------------------------------------------------------------------
__global__ __launch_bounds__(256) void moe_router(
    const void* __restrict__ xv, const void* __restrict__ Wrv,
    const int* __restrict__ flag,
    float* __restrict__ wbuf, int* __restrict__ idxbuf)
{
    const int t = blockIdx.x * 4 + (threadIdx.x >> 6);
    const int lane = threadIdx.x & 63;
    const bool isf32 = flag[0] != 0;

    float acc[NEXP];
#pragma unroll
    for (int e = 0; e < NEXP; ++e) acc[e] = 0.f;

    if (isf32) {
        const float* xr = (const float*)xv + (long long)t * DIM;
        const float* Wr = (const float*)Wrv;
        for (int it = 0; it < DIM / 64; ++it) {
            int d = it * 64 + lane;
            float xvv = xr[d];
            float4 wa = *(const float4*)(Wr + d * NEXP);
            float4 wb = *(const float4*)(Wr + d * NEXP + 4);
            acc[0] += xvv * wa.x; acc[1] += xvv * wa.y;
            acc[2] += xvv * wa.z; acc[3] += xvv * wa.w;
            acc[4] += xvv * wb.x; acc[5] += xvv * wb.y;
            acc[6] += xvv * wb.z; acc[7] += xvv * wb.w;
        }
    } else {
        const u16* xr = (const u16*)xv + (long long)t * DIM;
        const u16* Wr = (const u16*)Wrv;
        for (int it = 0; it < DIM / 64; ++it) {
            int d = it * 64 + lane;
            float xvv = b2f(xr[d]);
            uint4 wvv = *(const uint4*)(Wr + d * NEXP);
            const u16* ws = (const u16*)&wvv;
#pragma unroll
            for (int e = 0; e < NEXP; ++e) acc[e] += xvv * b2f(ws[e]);
        }
    }
#pragma unroll
    for (int off = 32; off; off >>= 1)
#pragma unroll
        for (int e = 0; e < NEXP; ++e) acc[e] += __shfl_xor(acc[e], off, 64);

    if (lane == 0) {
        float b1 = -3.4e38f, b2 = -3.4e38f; int i1 = 0, i2 = 0;
#pragma unroll
        for (int e = 0; e < NEXP; ++e) {
            float v = acc[e];
            if (v > b1) { b2 = b1; i2 = i1; b1 = v; i1 = e; }
            else if (v > b2) { b2 = v; i2 = e; }
        }
        float p2 = expf(b2 - b1);
        float inv = 1.0f / (1.0f + p2);
        wbuf[2 * t] = inv;       wbuf[2 * t + 1] = p2 * inv;
        idxbuf[2 * t] = i1;      idxbuf[2 * t + 1] = i2;
    }
}

// ---------------------------------------------------------------------------
// Bins: single wave, stable rank within expert == reference stable argsort.
// ---------------------------------------------------------------------------
__global__ void moe_bins(const int* __restrict__ idxbuf, int* __restrict__ slot_of,
                         int* __restrict__ token_of, int* __restrict__ rows_e)
{
    const int lane = threadIdx.x;
    const unsigned long long lmask = (1ull << lane) - 1ull;
    int cnt[NEXP];
#pragma unroll
    for (int q = 0; q < NEXP; ++q) cnt[q] = 0;

    for (int base = 0; base < T_TOK * 2; base += 256) {
        int e4[4];
#pragma unroll
        for (int u = 0; u < 4; ++u) e4[u] = idxbuf[base + u * 64 + lane];
#pragma unroll
        for (int u = 0; u < 4; ++u) {
            int e = e4[u];
            int ent = base + u * 64 + lane;
            int my = 0;
#pragma unroll
            for (int q = 0; q < NEXP; ++q) {
                unsigned long long bal = __ballot(e == q);
                if (e == q) my = cnt[q] + (int)__popcll(bal & lmask);
                cnt[q] += (int)__popcll(bal);
            }
            slot_of[ent] = my;
            if (my < CAP) token_of[e * CAP + my] = ent >> 1;
        }
    }
    if (lane == 0) {
#pragma unroll
        for (int q = 0; q < NEXP; ++q) rows_e[q] = cnt[q] < CAP ? cnt[q] : CAP;
    }
}

// ---------------------------------------------------------------------------
// Transpose [R][C] -> [C][R], output always bf16. z_eff = zBase + blockIdx.z
// selects input batch (element units of the runtime dtype).
// ---------------------------------------------------------------------------
__global__ __launch_bounds__(256) void moe_transpose(
    const void* __restrict__ inv, u16* __restrict__ out, const int* __restrict__ flag,
    int R, int C, int zBase, long long inBatch, long long outBatch)
{
    const int zi = zBase + blockIdx.z;
    const bool isf32 = flag[0] != 0;
    out += (long long)blockIdx.z * outBatch;
    const int c0 = blockIdx.x * 64, r0 = blockIdx.y * 64;

    __shared__ __align__(16) u16 tile[64][66];

    for (int g = threadIdx.x; g < 512; g += 256) {
        int r = g >> 3, c8 = (g & 7) * 8;
        long long off = (long long)zi * inBatch + (long long)(r0 + r) * C + c0 + c8;
        if (isf32) {
            const float* s = (const float*)inv + off;
            float4 a = *(const float4*)s;
            float4 b = *(const float4*)(s + 4);
            tile[r][c8 + 0] = f2b(a.x); tile[r][c8 + 1] = f2b(a.y);
            tile[r][c8 + 2] = f2b(a.z); tile[r][c8 + 3] = f2b(a.w);
            tile[r][c8 + 4] = f2b(b.x); tile[r][c8 + 5] = f2b(b.y);
            tile[r][c8 + 6] = f2b(b.z); tile[r][c8 + 7] = f2b(b.w);
        } else {
            uint4 v = *(const uint4*)((const u16*)inv + off);
            const u16* s = (const u16*)&v;
#pragma unroll
            for (int j = 0; j < 8; ++j) tile[r][c8 + j] = s[j];
        }
    }
    __syncthreads();
    for (int g = threadIdx.x; g < 512; g += 256) {
        int oc = g >> 3, orr = (g & 7) * 8;
        __align__(16) u16 vals[8];
#pragma unroll
        for (int j = 0; j < 8; ++j) vals[j] = tile[orr + j][oc];
        *(uint4*)&out[(long long)(c0 + oc) * R + r0 + orr] = *(const uint4*)vals;
    }
}

// ---------------------------------------------------------------------------
// 8-phase TN GEMM, read-ahead schedule. C[m][n]=act(sum_k A[m][k]*BT[n][k]).
// MODE 0: dense A (GEMM2). MODE 1: A=concat(xb,cb) by row, gelu.
// MODE 2: A gathered via token_of, gelu. BM=256, BK=64, 8 waves (2Mx4N).
// Frags double-buffered: a[qm-set], b[qn-set]; reads for phase p issued at
// p-1; MID wait = lgkmcnt(<reads issued at p>) -> p-1's reads complete in
// the shadow of p-1's MFMA region (LDS || matrix overlap).
// Per iteration (buf0=K-tile k0, phases 1-4; buf1=k0+1, phases 5-8):
//   p1: rdB(0,1)                      lgkm(RB) | Q(0,0)
//   p2: rdA(0,1) stA(0,0,kA)          lgkm(8)  | Q(0,1)
//   p3:          stB(0,0,kA)          lgkm(0)  | Q(1,0)  close: vmcnt(VMW)
//   p4: rdA(1,0) rdB(1,0) stB(0,1,kA) stA(0,1,kA)  (no lgkm) | Q(1,1)
//   p5: rdB(1,1)                      lgkm(RB) | Q(0,0)
//   p6: rdA(1,1) stA(1,0,kB)          lgkm(8)  | Q(0,1)
//   p7:          stB(1,0,kB)          lgkm(0)  | Q(1,0)  close: vmcnt(VMW)
//   p8: rdA(0,0) rdB(0,0) stB(1,1,kB) stA(1,1,kB)  (no lgkm) | Q(1,1)
// Ledger: vmcnt(VMW=2+SB) at p3 close keeps {p2,p3} -> drains prev p6,p7,p8
// = all buf1(k0+1) stages, before p4's buf1 reads (post-barrier). p7 close
// keeps {p6,p7} -> drains p2,p3,p4 = buf0(kA) stages, before p8's reads.
// WAR: each staged region's last reads were lgkm-drained >=1 barrier before
// the stage issues (qm0/qn0 drained p1/p5, qn1 p2/p6, qm1 p3/p7).
// kA/kB clamp to NKT-1 on the final iteration (dead stages, never used).
// ---------------------------------------------------------------------------

#define AIMM(buf, qm, f8) ((buf) * 32768 + (qm) * 16384 + (f8) * 2048)

#define READ_A(buf, qm) do { \
    a[qm][0][0] = dsr<AIMM(buf, qm, 0)>(aA0); a[qm][0][1] = dsr<AIMM(buf, qm, 0)>(aA1); \
    a[qm][1][0] = dsr<AIMM(buf, qm, 1)>(aA0); a[qm][1][1] = dsr<AIMM(buf, qm, 1)>(aA1); \
    a[qm][2][0] = dsr<AIMM(buf, qm, 2)>(aA0); a[qm][2][1] = dsr<AIMM(buf, qm, 2)>(aA1); \
    a[qm][3][0] = dsr<AIMM(buf, qm, 3)>(aA0); a[qm][3][1] = dsr<AIMM(buf, qm, 3)>(aA1); \
} while (0)

#define READ_B(buf, qn) do { \
    if constexpr (BN == 256) { \
        b[qn][0][0] = dsr<(buf) * 32768 + (qn) * 16384 + 0>(aB0); \
        b[qn][0][1] = dsr<(buf) * 32768 + (qn) * 16384 + 0>(aB1); \
        b[qn][1][0] = dsr<(buf) * 32768 + (qn) * 16384 + 2048>(aB0); \
        b[qn][1][1] = dsr<(buf) * 32768 + (qn) * 16384 + 2048>(aB1); \
    } else { \
        b[qn][0][0] = dsr<(buf) * 16384 + (qn) * 8192>(aB0); \
        b[qn][0][1] = dsr<(buf) * 16384 + (qn) * 8192>(aB1); \
    } \
} while (0)

// k outermost: consecutive MFMAs hit independent accumulators (no dep pairs).
#define MFMA_Q(qm, qn) do { \
    _Pragma("unroll") for (int k9 = 0; k9 < 2; ++k9) \
    _Pragma("unroll") for (int f9 = 0; f9 < 4; ++f9) \
    _Pragma("unroll") for (int n9 = 0; n9 < N9; ++n9) \
        acc[(qm) * 4 + f9][(qn) * N9 + n9] = __builtin_amdgcn_mfma_f32_16x16x32_bf16( \
            a[qm][f9][k9], b[qn][n9][k9], acc[(qm) * 4 + f9][(qn) * N9 + n9], 0, 0, 0); \
} while (0)

#define STAGE_A(buf, qm, kt) do { \
    const int ke7 = (kt) * 64; \
    _Pragma("unroll") for (int i7 = 0; i7 < 2; ++i7) { \
        const u16* src7; \
        if constexpr (MODE >= 1) { \
            src7 = (ke7 < DIM) \
                ? (const u16*)(A1b + offA1[i7][qm] + ke7 * 2) \
                : (const u16*)(A2b + offA2[i7][qm] + (ke7 - DIM) * 2); \
        } else { \
            src7 = (const u16*)(A1b + offA1[i7][qm] + ke7 * 2); \
        } \
        gload16(src7, &As[buf][qm][(wave * 64 + i7 * 512) * 8]); \
    } \
} while (0)

#define STAGE_B(buf, qn, kt) do { \
    const int ke7 = (kt) * 64; \
    _Pragma("unroll") for (int i7 = 0; i7 < SB; ++i7) \
        gload16((const u16*)(BTb + offB[i7][qn] + ke7 * 2), \
                &Bs[buf][qn][(wave * 64 + i7 * 512) * 8]); \
} while (0)

#define PH_MID(n) do { \
    __builtin_amdgcn_sched_barrier(0); \
    __builtin_amdgcn_s_barrier(); \
    lgkmw<n>(); \
    __builtin_amdgcn_sched_barrier(0); \
    __builtin_amdgcn_s_setprio(1); \
} while (0)
#define PH_MIDN() do { \
    __builtin_amdgcn_sched_barrier(0); \
    __builtin_amdgcn_s_barrier(); \
    __builtin_amdgcn_s_setprio(1); \
} while (0)
#define PH_CLOSE() do { \
    __builtin_amdgcn_s_setprio(0); \
    __builtin_amdgcn_sched_barrier(0); \
    __builtin_amdgcn_s_barrier(); \
    __builtin_amdgcn_sched_barrier(0); \
} while (0)
#define PH_CLOSE_VM() do { \
    __builtin_amdgcn_s_setprio(0); \
    vmwait<VMW>(); \
    __builtin_amdgcn_sched_barrier(0); \
    __builtin_amdgcn_s_barrier(); \
    __builtin_amdgcn_sched_barrier(0); \
} while (0)

template <int MODE, int KTOT, int BN>
__global__ __launch_bounds__(512, 2) void moe_gemm_8p(
    const u16* __restrict__ A1, const u16* __restrict__ A2,
    const u16* __restrict__ BT, u16* __restrict__ C,
    const int* __restrict__ tok_base, const int* __restrict__ rows_base,
    int ldC, long long aBatch, long long bBatch, long long cBatch)
{
    constexpr int NKT = KTOT / 64;
    static_assert((NKT & 1) == 0 && NKT >= 4, "K tiling");
    constexpr int N9  = BN / 128;   // col fragments per quadrant
    constexpr int SB  = BN / 128;   // B granules per thread per stage
    constexpr int VMW = 2 + SB;     // counted vmcnt at p3/p7 close
    constexpr int RB  = 2 * SB;     // ds_reads issued by READ_B

    // Bijective XCD swizzle (all grids have nwg % 8 == 0).
    const u32 nwg  = gridDim.x * gridDim.y;
    const u32 flat = blockIdx.y * gridDim.x + blockIdx.x;
    const u32 swz  = (flat & 7u) * (nwg >> 3) + (flat >> 3);
    const int bx = (int)(swz % gridDim.x);
    const int by = (int)(swz / gridDim.x);

    const int z = blockIdx.z;
    int rows = 1 << 30;
    if (rows_base) {
        rows = rows_base[z];
        if (by * 256 >= rows) return;
    }

    __shared__ __align__(16) u16 As[2][2][8192];      // 64 KiB
    __shared__ __align__(16) u16 Bs[2][2][BN * 32];   // 64 or 32 KiB

    const int tid  = threadIdx.x;
    const int lane = tid & 63;
    const int wave = tid >> 6;
    const int wmw  = wave >> 2;     // 0..1
    const int wnw  = wave & 3;      // 0..3
    const int m0 = by * 256;
    const int n0 = bx * BN;

    const char* A1b = (const char*)(MODE == 0 ? A1 + (long long)z * aBatch : A1);
    const char* A2b = (const char*)A2;
    const char* BTb = (const char*)(BT + (long long)z * bBatch);

    // Per-thread staging byte offsets (source pre-swizzled: c16 ^= row&7).
    u32 offA1[2][2], offA2[2][2], offB[SB][2];
#pragma unroll
    for (int i = 0; i < 2; ++i) {
        const int g = tid + i * 512;
        const int wm = g >> 9, r = (g >> 3) & 63, c16 = g & 7;
        const int cs = (c16 ^ (r & 7)) * 8;
#pragma unroll
        for (int qm = 0; qm < 2; ++qm) {
            const int rg = m0 + wm * 128 + qm * 64 + r;
            if constexpr (MODE == 2) {
                const int* tok = tok_base + (long long)z * CAP;
                const int tk = (rg < rows) ? tok[rg] : 0;
                offA1[i][qm] = (u32)((tk * DIM + cs) * 2);
                offA2[i][qm] = (u32)((tk * DCOND + cs) * 2);
            } else if constexpr (MODE == 1) {
                offA1[i][qm] = (u32)((rg * DIM + cs) * 2);
                offA2[i][qm] = (u32)((rg * DCOND + cs) * 2);
            } else {
                offA1[i][qm] = (u32)(((long long)rg * KTOT + cs) * 2);
                offA2[i][qm] = 0;
            }
        }
    }
#pragma unroll
    for (int i = 0; i < SB; ++i) {
        const int g = tid + i * 512;
        int wn, c;
        if constexpr (BN == 256) { wn = g >> 8; c = (g >> 3) & 31; }
        else                     { wn = g >> 7; c = (g >> 3) & 15; }
        const int c16 = g & 7;
        const int cs = (c16 ^ (c & 7)) * 8;
#pragma unroll
        for (int qn = 0; qn < 2; ++qn) {
            const int cbl = (BN == 256) ? (wn * 64 + qn * 32 + c)
                                        : (wn * 32 + qn * 16 + c);
            offB[i][qn] = (u32)(((long long)(n0 + cbl) * KTOT + cs) * 2);
        }
    }

    // LDS read base addresses (as3, byte units). Swizzle XOR folded per kk.
    const u32 AsB = (u32)(size_t)(__attribute__((address_space(3))) u16*)&As[0][0][0];
    const u32 BsB = (u32)(size_t)(__attribute__((address_space(3))) u16*)&Bs[0][0][0];
    const int lrow = lane & 15;
    const int x0 = (((lane >> 4) + 0) ^ (lane & 7)) << 4;
    const int x4 = (((lane >> 4) + 4) ^ (lane & 7)) << 4;
    const u32 aA0 = AsB + (u32)((wmw * 64 + lrow) * 128 + x0);
    const u32 aA1 = AsB + (u32)((wmw * 64 + lrow) * 128 + x4);
    const int bro = (BN == 256 ? wnw * 32 : wnw * 16) + lrow;
    const u32 aB0 = BsB + (u32)(bro * 128 + x0);
    const u32 aB1 = BsB + (u32)(bro * 128 + x4);

    f32x4 acc[8][2 * N9];
#pragma unroll
    for (int m = 0; m < 8; ++m)
#pragma unroll
        for (int n = 0; n < 2 * N9; ++n) { f32x4 zv = {0.f, 0.f, 0.f, 0.f}; acc[m][n] = zv; }

    bf16x8 a[2][4][2];      // [qm-set][frag][kk]
    bf16x8 b[2][N9][2];     // [qn-set][frag][kk]

    // Prologue: stage K0 -> buf0 and K1 -> buf1 fully; wait buf0 (leaves
    // buf1's 4+2*SB in flight); barrier; read-ahead for p1 (Q(0,0) frags).
    STAGE_A(0, 0, 0); STAGE_B(0, 0, 0); STAGE_A(0, 1, 0); STAGE_B(0, 1, 0);
    STAGE_A(1, 0, 1); STAGE_B(1, 0, 1); STAGE_A(1, 1, 1); STAGE_B(1, 1, 1);
    vmwait<4 + 2 * SB>();
    __builtin_amdgcn_sched_barrier(0);
    __builtin_amdgcn_s_barrier();
    __builtin_amdgcn_sched_barrier(0);
    READ_A(0, 0); READ_B(0, 0);

#pragma unroll 1
    for (int t = 0; t < NKT / 2; ++t) {
        const int k2 = 2 * t;
        const int kA = (k2 + 2 < NKT) ? k2 + 2 : NKT - 1;
        const int kB = (k2 + 3 < NKT) ? k2 + 3 : NKT - 1;
        // -- phase 1
        READ_B(0, 1);
        PH_MID(RB);  MFMA_Q(0, 0); PH_CLOSE();
        // -- phase 2
        READ_A(0, 1); STAGE_A(0, 0, kA);
        PH_MID(8);   MFMA_Q(0, 1); PH_CLOSE();
        // -- phase 3
        STAGE_B(0, 0, kA);
        PH_MID(0);   MFMA_Q(1, 0); PH_CLOSE_VM();
        // -- phase 4
        READ_A(1, 0); READ_B(1, 0); STAGE_B(0, 1, kA); STAGE_A(0, 1, kA);
        PH_MIDN();   MFMA_Q(1, 1); PH_CLOSE();
        // -- phase 5
        READ_B(1, 1);
        PH_MID(RB);  MFMA_Q(0, 0); PH_CLOSE();
        // -- phase 6
        READ_A(1, 1); STAGE_A(1, 0, kB);
        PH_MID(8);   MFMA_Q(0, 1); PH_CLOSE();
        // -- phase 7
        STAGE_B(1, 0, kB);
        PH_MID(0);   MFMA_Q(1, 0); PH_CLOSE_VM();
        // -- phase 8
        READ_A(0, 0); READ_B(0, 0); STAGE_B(1, 1, kB); STAGE_A(1, 1, kB);
        PH_MIDN();   MFMA_Q(1, 1); PH_CLOSE();
    }
    // Drain dangling read-ahead + dead stages before epilogue.
    lgkmw<0>();
    vmwait<0>();

    // Epilogue. C/D layout: col=lane&15, row=(lane>>4)*4+reg (m89/m91).
    u16* Cz = C + (long long)z * cBatch;
#pragma unroll
    for (int m = 0; m < 8; ++m) {
        const int rowb = m0 + wmw * 128 + (m >> 2) * 64 + (m & 3) * 16 + (lane >> 4) * 4;
#pragma unroll
        for (int n = 0; n < 2 * N9; ++n) {
            int col;
            if constexpr (BN == 256)
                col = n0 + wnw * 64 + (n >> 1) * 32 + (n & 1) * 16 + (lane & 15);
            else
                col = n0 + wnw * 32 + n * 16 + (lane & 15);
#pragma unroll
            for (int rr = 0; rr < 4; ++rr) {
                float v = acc[m][n][rr];
                if constexpr (MODE >= 1) v = gelu_f(v);
                Cz[(long long)(rowb + rr) * ldC + col] = f2b(v);
            }
        }
    }
}

// ---------------------------------------------------------------------------
// Combine: out[t] = mask[t]*(xs[t] + 2*(w1*v1*y[e1,p1] + w2*v2*y[e2,p2]))/3
// ---------------------------------------------------------------------------
__global__ __launch_bounds__(256) void moe_combine(
    const u16* __restrict__ xs, const u16* __restrict__ y,
    const float* __restrict__ wbuf, const int* __restrict__ idxbuf,
    const int* __restrict__ slot_of, const void* __restrict__ maskv,
    void* __restrict__ outv, const int* __restrict__ flag)
{
    const int t = blockIdx.x;
    const int c = threadIdx.x * 4;
    const bool isf32 = flag[0] != 0;
    const float mk = isf32 ? ((const float*)maskv)[t] : b2f(((const u16*)maskv)[t]);

    int e1 = idxbuf[2 * t], e2 = idxbuf[2 * t + 1];
    int s1 = slot_of[2 * t], s2 = slot_of[2 * t + 1];
    float w1 = wbuf[2 * t], w2 = wbuf[2 * t + 1];
    float g1 = (s1 < CAP) ? w1 : 0.f;
    float g2 = (s2 < CAP) ? w2 : 0.f;
    int r1 = s1 < CAP ? s1 : CAP - 1;
    int r2 = s2 < CAP ? s2 : CAP - 1;

    uint2 xvv = *(const uint2*)(xs + (long long)t * DIM + c);
    uint2 y1 = *(const uint2*)(y + ((long long)e1 * CAP + r1) * DIM + c);
    uint2 y2 = *(const uint2*)(y + ((long long)e2 * CAP + r2) * DIM + c);
    const u16* xp = (const u16*)&xvv;
    const u16* p1 = (const u16*)&y1;
    const u16* p2 = (const u16*)&y2;

    float o[4];
#pragma unroll
    for (int q = 0; q < 4; ++q) {
        float v = (b2f(xp[q]) + 2.f * (g1 * b2f(p1[q]) + g2 * b2f(p2[q]))) * mk * (1.f / 3.f);
        o[q] = (v == v) ? v : 0.f;
    }
    if (isf32) {
        float4 o4 = {o[0], o[1], o[2], o[3]};
        *(float4*)((float*)outv + (long long)t * DIM + c) = o4;
    } else {
        __align__(8) u16 ov[4];
#pragma unroll
        for (int q = 0; q < 4; ++q) ov[q] = f2b(o[q]);
        *(uint2*)((u16*)outv + (long long)t * DIM + c) = *(const uint2*)ov;
    }
}

// ---------------------------------------------------------------------------
extern "C" void kernel_launch(void* const* d_in, const int* in_sizes, int n_in,
                              void* d_out, int out_size, void* d_ws, size_t ws_size,
                              hipStream_t stream)
{
    const void* x    = d_in[0];
    const void* cond = d_in[1];
    const void* mask = d_in[2];
    const void* Wr   = d_in[3];
    const void* W1s  = d_in[4];
    const void* W2s  = d_in[5];
    const void* W1e  = d_in[6];
    const void* W2e  = d_in[7];

    const int KIN = DIM + DCOND;   // 1280
    const int EGX = 3;             // max experts per group ({3,3,2} grouping)

    // Workspace carve (~223 MB; round-1/2 proved >=237 MB mapped).
    char* p = (char*)d_ws;
    u16* W1sT   = (u16*)p; p += (long long)DFF * KIN * 2;          // 10.5 MB
    u16* W2sT   = (u16*)p; p += (long long)DIM * DFF * 2;          //  8.4 MB
    u16* W1eT   = (u16*)p; p += (long long)EGX * DFF * KIN * 2;    // 31.5 MB
    u16* W2eT   = (u16*)p; p += (long long)EGX * DIM * DFF * 2;    // 25.2 MB
    u16* h      = (u16*)p; p += (long long)T_TOK * DFF * 2;        // 67.1 MB (>= EGX*CAP*DFF)
    u16* xs     = (u16*)p; p += (long long)T_TOK * DIM * 2;        // 16.8 MB
    u16* y      = (u16*)p; p += (long long)NEXP * CAP * DIM * 2;   // 41.9 MB
    u16* xb     = (u16*)p; p += (long long)T_TOK * DIM * 2;        // 16.8 MB
    u16* cb     = (u16*)p; p += (long long)T_TOK * DCOND * 2;      //  4.2 MB
    float* wbuf = (float*)p; p += T_TOK * 2 * sizeof(float);
    int* idxbuf = (int*)p;   p += T_TOK * 2 * sizeof(int);
    int* slot_of = (int*)p;  p += T_TOK * 2 * sizeof(int);
    int* token_of = (int*)p; p += NEXP * CAP * sizeof(int);
    int* rows_e = (int*)p;   p += 256;
    int* flag   = (int*)p;   p += 256;
    (void)ws_size; (void)in_sizes; (void)n_in; (void)out_size;

    dim3 b256(256);
    dim3 b512(512);

    moe_probe<<<dim3(1), dim3(64), 0, stream>>>((const u16*)x, flag);

    // Normalize activations to bf16 once (GEMMs become single-path DMA).
    moe_cvt<<<dim3(T_TOK * DIM / (256 * 8)), b256, 0, stream>>>(x, xb, flag);
    moe_cvt<<<dim3(T_TOK * DCOND / (256 * 8)), b256, 0, stream>>>(cond, cb, flag);

    moe_router<<<dim3(T_TOK / 4), b256, 0, stream>>>(x, Wr, flag, wbuf, idxbuf);
    moe_bins<<<dim3(1), dim3(64), 0, stream>>>(idxbuf, slot_of, token_of, rows_e);

    moe_transpose<<<dim3(DFF / 64, KIN / 64, 1), b256, 0, stream>>>(
        W1s, W1sT, flag, KIN, DFF, 0, 0, 0);
    moe_transpose<<<dim3(DIM / 64, DFF / 64, 1), b256, 0, stream>>>(
        W2s, W2sT, flag, DFF, DIM, 0, 0, 0);

    // Shared expert: h = gelu([xb|cb] @ W1s); xs = h @ W2s.
    moe_gemm_8p<1, 1280, 256><<<dim3(DFF / 256, T_TOK / 256, 1), b512, 0, stream>>>(
        xb, cb, W1sT, h, nullptr, nullptr, DFF, 0, 0, 0);
    moe_gemm_8p<0, 4096, 128><<<dim3(DIM / 128, T_TOK / 256, 1), b512, 0, stream>>>(
        h, nullptr, W2sT, xs, nullptr, nullptr, DIM, 0, 0, 0);

    // Routed experts, groups of {3,3,2} (z-batched).
    const int gsz[3] = {3, 3, 2};
    int gb = 0;
    for (int gi = 0; gi < 3; ++gi) {
        const int eg = gsz[gi];
        moe_transpose<<<dim3(DFF / 64, KIN / 64, eg), b256, 0, stream>>>(
            W1e, W1eT, flag, KIN, DFF, gb,
            (long long)KIN * DFF, (long long)DFF * KIN);
        moe_transpose<<<dim3(DIM / 64, DFF / 64, eg), b256, 0, stream>>>(
            W2e, W2eT, flag, DFF, DIM, gb,
            (long long)DFF * DIM, (long long)DIM * DFF);

        moe_gemm_8p<2, 1280, 256><<<dim3(DFF / 256, CAP / 256, eg), b512, 0, stream>>>(
            xb, cb, W1eT, h, token_of + (long long)gb * CAP, rows_e + gb,
            DFF, 0, (long long)DFF * KIN, (long long)CAP * DFF);
        moe_gemm_8p<0, 4096, 128><<<dim3(DIM / 128, CAP / 256, eg), b512, 0, stream>>>(
            h, nullptr, W2eT, y + (long long)gb * CAP * DIM, nullptr, rows_e + gb,
            DIM, (long long)CAP * DFF, (long long)DIM * DFF, (long long)CAP * DIM);
        gb += eg;
    }

    moe_combine<<<dim3(T_TOK), b256, 0, stream>>>(xs, y, wbuf, idxbuf, slot_of, mask, d_out, flag);
}

// Round 4
// 1142.012 us; speedup vs baseline: 1.1444x; 1.1444x over previous
//
#include <hip/hip_runtime.h>

// ---------------------------------------------------------------------------
// MoE (b=4,n=2048,d=1024,dc=256,dff=4096,E=8,K=2,cap=2560). Pipeline:
//   probe -> cvt(x,cond->bf16) -> router(f32) -> bins ->
//   transpose weights(->bf16) -> GEMM1 (4-phase 256x256, gelu) ->
//   GEMM2 (4-phase 256x128) -> combine.
// 4-phase template v4 (post round-3 spill regression): fragments SINGLE-set
// (a[4][2], b[2][N9][2] -- 64 VGPR; 8-wave 256^2 has a hard 256-reg budget:
// acc 128 + frags + addr must fit; round-3's doubled frags spilled, WRITE
// 65.5->133 MB). Two zero-register levers instead:
//  (1) 4 phases/iter (2 per K-tile, 32 MFMA/phase): halves barrier+wait
//      events, doubles matrix work per overhead event.
//  (2) ONE barrier per phase (close only). Proof: every wave's lgkmcnt(0)
//      precedes its close-barrier, so any wave past close(p) implies ALL
//      waves' phase-p LDS reads are complete -> phase p+1 stages are WAR-
//      safe. Staged-data RAW guarded by counted vmcnt+barrier at II/IV.
//      No mid-barrier -> waves skew within a phase -> late waves' ds_reads
//      execute under early waves' MFMAs (LDS || matrix overlap).
// Per iteration (buf0 = K-tile k2, buf1 = k2+1):
//   I:   stage A(1,1)<-k2+1          | rd A(0,0) B(0,0) B(0,1) | MFMA_P(0)
//   II:  stage A(0,0),B(0,0),B(0,1)<-kA | rd A(0,1)            | MFMA_P(1) +vm
//   III: stage A(0,1)<-kA            | rd A(1,0) B(1,0) B(1,1) | MFMA_P(0)
//   IV:  stage A(1,0),B(1,0),B(1,1)<-kB | rd A(1,1)            | MFMA_P(1) +vm
// Ledger (BN=256, gloads/thread: I=2,II=6,III=2,IV=6): at II-close
// outstanding = prevIV 6 + I 2 + II 6 = 14, vmcnt(6) keeps II's -> prevIV+I
// landed = buf1(k2+1) complete before III reads. At IV-close = II6+III2+IV6,
// vmcnt(6) -> II+III landed = buf0(kA) complete before next-I. BN=128 halves
// B-stages: vmcnt(4). kA/kB clamp to NKT-1 on final iter (dead, never read).
// WAR: each staged region's last read is in the previous phase, drained by
// that phase's lgkmcnt(0) before its close-barrier.
// ---------------------------------------------------------------------------

typedef unsigned short u16;
typedef unsigned int u32;
typedef __bf16 bf16x8 __attribute__((ext_vector_type(8)));
typedef float f32x4 __attribute__((ext_vector_type(4)));

constexpr int T_TOK = 8192;
constexpr int DIM   = 1024;
constexpr int DCOND = 256;
constexpr int DFF   = 4096;
constexpr int NEXP  = 8;
constexpr int CAP   = 2560;   // int(1.25 * 2 * 8192 / 8)

__device__ __forceinline__ float b2f(u16 u) {
    union { u32 u; float f; } v; v.u = (u32)u << 16; return v.f;
}
__device__ __forceinline__ u16 f2b(float f) {
    union { float f; u32 u; } v; v.f = f;
    u32 r = (v.u + 0x7fffu + ((v.u >> 16) & 1u)) >> 16;
    return (u16)r;
}
// Fast tanh-gelu: tanh(z) = 1 - 2/(exp(2z)+1). Matches tanhf to ~1e-6.
__device__ __forceinline__ float gelu_f(float x) {
    if (!(x == x)) x = 0.f;
    x = fminf(1e4f, fmaxf(-1e4f, x));
    float z = 0.7978845608028654f * (x + 0.044715f * x * x * x);
    float e = __expf(2.0f * z);
    float th = 1.0f - 2.0f / (e + 1.0f);
    return 0.5f * x * (1.0f + th);
}

// global -> LDS DMA, 16 B per lane; LDS dest is wave-uniform base + lane*16.
__device__ __forceinline__ void gload16(const u16* g, u16* l) {
    __builtin_amdgcn_global_load_lds(
        (const __attribute__((address_space(1))) void*)g,
        (__attribute__((address_space(3))) void*)l, 16, 0, 0);
}

// Inline-asm LDS read (opaque to the memory legalizer: no vmcnt(0) ordering
// vs the global_load_lds DMA). IMM: compile-time byte offset.
template <int IMM>
__device__ __forceinline__ bf16x8 dsr(u32 addr) {
    bf16x8 d;
    asm volatile("ds_read_b128 %0, %1 offset:%2" : "=v"(d) : "v"(addr), "n"(IMM));
    return d;
}
template <int N>
__device__ __forceinline__ void vmwait() {
    asm volatile("s_waitcnt vmcnt(%0)" :: "n"(N) : "memory");
}
__device__ __forceinline__ void lgkm0() {
    asm volatile("s_waitcnt lgkmcnt(0)" ::: "memory");
}

// ---------------------------------------------------------------------------
// Dtype probe: flag=1 means inputs are float32.
// ---------------------------------------------------------------------------
__global__ void moe_probe(const u16* __restrict__ x, int* __restrict__ flag) {
    const int lane = threadIdx.x;   // 64 threads
    int cnt = 0;
    for (int i = lane; i < 4096; i += 64) {
        int e = (x[i] >> 7) & 0xFF;
        cnt += (e >= 0xC8);
    }
#pragma unroll
    for (int off = 32; off; off >>= 1) cnt += __shfl_xor(cnt, off, 64);
    if (lane == 0) flag[0] = (cnt > 8) ? 1 : 0;
}

// ---------------------------------------------------------------------------
// cvt: normalize a tensor to bf16 (straight copy if already bf16).
// ---------------------------------------------------------------------------
__global__ __launch_bounds__(256) void moe_cvt(
    const void* __restrict__ in, u16* __restrict__ out,
    const int* __restrict__ flag)
{
    const long long i = ((long long)blockIdx.x * 256 + threadIdx.x) * 8;
    if (flag[0]) {
        const float* s = (const float*)in + i;
        float4 a = *(const float4*)s;
        float4 b = *(const float4*)(s + 4);
        __align__(16) u16 t8[8];
        t8[0] = f2b(a.x); t8[1] = f2b(a.y); t8[2] = f2b(a.z); t8[3] = f2b(a.w);
        t8[4] = f2b(b.x); t8[5] = f2b(b.y); t8[6] = f2b(b.z); t8[7] = f2b(b.w);
        *(uint4*)(out + i) = *(const uint4*)t8;
    } else {
        *(uint4*)(out + i) = *(const uint4*)((const u16*)in + i);
    }
}

// ---------------------------------------------------------------------------
// Router: one wave per token, f32 logits (reads ORIGINAL x so top-k ties
// match the f32 reference), top-2 lower-index-wins, 2-way softmax weights.
// ---------------------------------------------------------------------------
__global__ __launch_bounds__(256) void moe_router(
    const void* __restrict__ xv, const void* __restrict__ Wrv,
    const int* __restrict__ flag,
    float* __restrict__ wbuf, int* __restrict__ idxbuf)
{
    const int t = blockIdx.x * 4 + (threadIdx.x >> 6);
    const int lane = threadIdx.x & 63;
    const bool isf32 = flag[0] != 0;

    float acc[NEXP];
#pragma unroll
    for (int e = 0; e < NEXP; ++e) acc[e] = 0.f;

    if (isf32) {
        const float* xr = (const float*)xv + (long long)t * DIM;
        const float* Wr = (const float*)Wrv;
        for (int it = 0; it < DIM / 64; ++it) {
            int d = it * 64 + lane;
            float xvv = xr[d];
            float4 wa = *(const float4*)(Wr + d * NEXP);
            float4 wb = *(const float4*)(Wr + d * NEXP + 4);
            acc[0] += xvv * wa.x; acc[1] += xvv * wa.y;
            acc[2] += xvv * wa.z; acc[3] += xvv * wa.w;
            acc[4] += xvv * wb.x; acc[5] += xvv * wb.y;
            acc[6] += xvv * wb.z; acc[7] += xvv * wb.w;
        }
    } else {
        const u16* xr = (const u16*)xv + (long long)t * DIM;
        const u16* Wr = (const u16*)Wrv;
        for (int it = 0; it < DIM / 64; ++it) {
            int d = it * 64 + lane;
            float xvv = b2f(xr[d]);
            uint4 wvv = *(const uint4*)(Wr + d * NEXP);
            const u16* ws = (const u16*)&wvv;
#pragma unroll
            for (int e = 0; e < NEXP; ++e) acc[e] += xvv * b2f(ws[e]);
        }
    }
#pragma unroll
    for (int off = 32; off; off >>= 1)
#pragma unroll
        for (int e = 0; e < NEXP; ++e) acc[e] += __shfl_xor(acc[e], off, 64);

    if (lane == 0) {
        float b1 = -3.4e38f, b2 = -3.4e38f; int i1 = 0, i2 = 0;
#pragma unroll
        for (int e = 0; e < NEXP; ++e) {
            float v = acc[e];
            if (v > b1) { b2 = b1; i2 = i1; b1 = v; i1 = e; }
            else if (v > b2) { b2 = v; i2 = e; }
        }
        float p2 = expf(b2 - b1);
        float inv = 1.0f / (1.0f + p2);
        wbuf[2 * t] = inv;       wbuf[2 * t + 1] = p2 * inv;
        idxbuf[2 * t] = i1;      idxbuf[2 * t + 1] = i2;
    }
}

// ---------------------------------------------------------------------------
// Bins: single wave, stable rank within expert == reference stable argsort.
// ---------------------------------------------------------------------------
__global__ void moe_bins(const int* __restrict__ idxbuf, int* __restrict__ slot_of,
                         int* __restrict__ token_of, int* __restrict__ rows_e)
{
    const int lane = threadIdx.x;
    const unsigned long long lmask = (1ull << lane) - 1ull;
    int cnt[NEXP];
#pragma unroll
    for (int q = 0; q < NEXP; ++q) cnt[q] = 0;

    for (int base = 0; base < T_TOK * 2; base += 256) {
        int e4[4];
#pragma unroll
        for (int u = 0; u < 4; ++u) e4[u] = idxbuf[base + u * 64 + lane];
#pragma unroll
        for (int u = 0; u < 4; ++u) {
            int e = e4[u];
            int ent = base + u * 64 + lane;
            int my = 0;
#pragma unroll
            for (int q = 0; q < NEXP; ++q) {
                unsigned long long bal = __ballot(e == q);
                if (e == q) my = cnt[q] + (int)__popcll(bal & lmask);
                cnt[q] += (int)__popcll(bal);
            }
            slot_of[ent] = my;
            if (my < CAP) token_of[e * CAP + my] = ent >> 1;
        }
    }
    if (lane == 0) {
#pragma unroll
        for (int q = 0; q < NEXP; ++q) rows_e[q] = cnt[q] < CAP ? cnt[q] : CAP;
    }
}

// ---------------------------------------------------------------------------
// Transpose [R][C] -> [C][R], output always bf16. z_eff = zBase + blockIdx.z
// selects input batch (element units of the runtime dtype).
// ---------------------------------------------------------------------------
__global__ __launch_bounds__(256) void moe_transpose(
    const void* __restrict__ inv, u16* __restrict__ out, const int* __restrict__ flag,
    int R, int C, int zBase, long long inBatch, long long outBatch)
{
    const int zi = zBase + blockIdx.z;
    const bool isf32 = flag[0] != 0;
    out += (long long)blockIdx.z * outBatch;
    const int c0 = blockIdx.x * 64, r0 = blockIdx.y * 64;

    __shared__ __align__(16) u16 tile[64][66];

    for (int g = threadIdx.x; g < 512; g += 256) {
        int r = g >> 3, c8 = (g & 7) * 8;
        long long off = (long long)zi * inBatch + (long long)(r0 + r) * C + c0 + c8;
        if (isf32) {
            const float* s = (const float*)inv + off;
            float4 a = *(const float4*)s;
            float4 b = *(const float4*)(s + 4);
            tile[r][c8 + 0] = f2b(a.x); tile[r][c8 + 1] = f2b(a.y);
            tile[r][c8 + 2] = f2b(a.z); tile[r][c8 + 3] = f2b(a.w);
            tile[r][c8 + 4] = f2b(b.x); tile[r][c8 + 5] = f2b(b.y);
            tile[r][c8 + 6] = f2b(b.z); tile[r][c8 + 7] = f2b(b.w);
        } else {
            uint4 v = *(const uint4*)((const u16*)inv + off);
            const u16* s = (const u16*)&v;
#pragma unroll
            for (int j = 0; j < 8; ++j) tile[r][c8 + j] = s[j];
        }
    }
    __syncthreads();
    for (int g = threadIdx.x; g < 512; g += 256) {
        int oc = g >> 3, orr = (g & 7) * 8;
        __align__(16) u16 vals[8];
#pragma unroll
        for (int j = 0; j < 8; ++j) vals[j] = tile[orr + j][oc];
        *(uint4*)&out[(long long)(c0 + oc) * R + r0 + orr] = *(const uint4*)vals;
    }
}

// ---------------------------------------------------------------------------
// 4-phase TN GEMM. See file header for schedule + ledger.
// MODE 0: dense A (GEMM2). MODE 1: A=concat(xb,cb) by row, gelu.
// MODE 2: A gathered via token_of, gelu. BM=256, BK=64, 8 waves (2Mx4N).
// ---------------------------------------------------------------------------

#define AIMM(buf, qm, f8) ((buf) * 32768 + (qm) * 16384 + (f8) * 2048)

#define READ_A(buf, qm) do { \
    a[0][0] = dsr<AIMM(buf, qm, 0)>(aA0); a[0][1] = dsr<AIMM(buf, qm, 0)>(aA1); \
    a[1][0] = dsr<AIMM(buf, qm, 1)>(aA0); a[1][1] = dsr<AIMM(buf, qm, 1)>(aA1); \
    a[2][0] = dsr<AIMM(buf, qm, 2)>(aA0); a[2][1] = dsr<AIMM(buf, qm, 2)>(aA1); \
    a[3][0] = dsr<AIMM(buf, qm, 3)>(aA0); a[3][1] = dsr<AIMM(buf, qm, 3)>(aA1); \
} while (0)

#define READ_B(buf, qn) do { \
    if constexpr (BN == 256) { \
        b[qn][0][0] = dsr<(buf) * 32768 + (qn) * 16384 + 0>(aB0); \
        b[qn][0][1] = dsr<(buf) * 32768 + (qn) * 16384 + 0>(aB1); \
        b[qn][1][0] = dsr<(buf) * 32768 + (qn) * 16384 + 2048>(aB0); \
        b[qn][1][1] = dsr<(buf) * 32768 + (qn) * 16384 + 2048>(aB1); \
    } else { \
        b[qn][0][0] = dsr<(buf) * 16384 + (qn) * 8192>(aB0); \
        b[qn][0][1] = dsr<(buf) * 16384 + (qn) * 8192>(aB1); \
    } \
} while (0)

// Full acc-row sweep for quadrant-row qm: 32 MFMA (BN=256) / 16 (BN=128).
// k outer, then f/qn/n: consecutive MFMAs hit independent accumulators.
#define MFMA_P(qm) do { \
    _Pragma("unroll") for (int k9 = 0; k9 < 2; ++k9) \
    _Pragma("unroll") for (int f9 = 0; f9 < 4; ++f9) \
    _Pragma("unroll") for (int q9 = 0; q9 < 2; ++q9) \
    _Pragma("unroll") for (int n9 = 0; n9 < N9; ++n9) \
        acc[(qm) * 4 + f9][q9 * N9 + n9] = __builtin_amdgcn_mfma_f32_16x16x32_bf16( \
            a[f9][k9], b[q9][n9][k9], acc[(qm) * 4 + f9][q9 * N9 + n9], 0, 0, 0); \
} while (0)

#define STAGE_A(buf, qm, kt) do { \
    const int ke7 = (kt) * 64; \
    _Pragma("unroll") for (int i7 = 0; i7 < 2; ++i7) { \
        const u16* src7; \
        if constexpr (MODE >= 1) { \
            src7 = (ke7 < DIM) \
                ? (const u16*)(A1b + offA1[i7][qm] + ke7 * 2) \
                : (const u16*)(A2b + offA2[i7][qm] + (ke7 - DIM) * 2); \
        } else { \
            src7 = (const u16*)(A1b + offA1[i7][qm] + ke7 * 2); \
        } \
        gload16(src7, &As[buf][qm][(wave * 64 + i7 * 512) * 8]); \
    } \
} while (0)

#define STAGE_B(buf, qn, kt) do { \
    const int ke7 = (kt) * 64; \
    _Pragma("unroll") for (int i7 = 0; i7 < SB; ++i7) \
        gload16((const u16*)(BTb + offB[i7][qn] + ke7 * 2), \
                &Bs[buf][qn][(wave * 64 + i7 * 512) * 8]); \
} while (0)

// Wait for this phase's ds_reads; rule-18 fence so MFMA can't hoist above.
#define PH_WAIT() do { \
    lgkm0(); \
    __builtin_amdgcn_sched_barrier(0); \
    __builtin_amdgcn_s_setprio(1); \
} while (0)
// Close: single barrier per phase. All waves' lgkm0 precede their close ->
// after close, all reads of this phase's regions are complete (WAR-safe).
#define PH_END() do { \
    __builtin_amdgcn_s_setprio(0); \
    __builtin_amdgcn_s_barrier(); \
} while (0)
#define PH_END_VM() do { \
    __builtin_amdgcn_s_setprio(0); \
    vmwait<VMW>(); \
    __builtin_amdgcn_s_barrier(); \
} while (0)

template <int MODE, int KTOT, int BN>
__global__ __launch_bounds__(512, 2) void moe_gemm_4p(
    const u16* __restrict__ A1, const u16* __restrict__ A2,
    const u16* __restrict__ BT, u16* __restrict__ C,
    const int* __restrict__ tok_base, const int* __restrict__ rows_base,
    int ldC, long long aBatch, long long bBatch, long long cBatch)
{
    constexpr int NKT = KTOT / 64;
    static_assert((NKT & 1) == 0 && NKT >= 4, "K tiling");
    constexpr int N9  = BN / 128;   // col fragments per quadrant
    constexpr int SB  = BN / 128;   // B granules per thread per stage
    constexpr int VMW = 2 + 2 * SB; // counted vmcnt at II/IV close

    // Bijective XCD swizzle (all grids have nwg % 8 == 0).
    const u32 nwg  = gridDim.x * gridDim.y;
    const u32 flat = blockIdx.y * gridDim.x + blockIdx.x;
    const u32 swz  = (flat & 7u) * (nwg >> 3) + (flat >> 3);
    const int bx = (int)(swz % gridDim.x);
    const int by = (int)(swz / gridDim.x);

    const int z = blockIdx.z;
    int rows = 1 << 30;
    if (rows_base) {
        rows = rows_base[z];
        if (by * 256 >= rows) return;
    }

    __shared__ __align__(16) u16 As[2][2][8192];      // 64 KiB
    __shared__ __align__(16) u16 Bs[2][2][BN * 32];   // 64 or 32 KiB

    const int tid  = threadIdx.x;
    const int lane = tid & 63;
    const int wave = tid >> 6;
    const int wmw  = wave >> 2;     // 0..1
    const int wnw  = wave & 3;      // 0..3
    const int m0 = by * 256;
    const int n0 = bx * BN;

    const char* A1b = (const char*)(MODE == 0 ? A1 + (long long)z * aBatch : A1);
    const char* A2b = (const char*)A2;
    const char* BTb = (const char*)(BT + (long long)z * bBatch);

    // Per-thread staging byte offsets (source pre-swizzled: c16 ^= row&7).
    u32 offA1[2][2], offA2[2][2], offB[SB][2];
#pragma unroll
    for (int i = 0; i < 2; ++i) {
        const int g = tid + i * 512;
        const int wm = g >> 9, r = (g >> 3) & 63, c16 = g & 7;
        const int cs = (c16 ^ (r & 7)) * 8;
#pragma unroll
        for (int qm = 0; qm < 2; ++qm) {
            const int rg = m0 + wm * 128 + qm * 64 + r;
            if constexpr (MODE == 2) {
                const int* tok = tok_base + (long long)z * CAP;
                const int tk = (rg < rows) ? tok[rg] : 0;
                offA1[i][qm] = (u32)((tk * DIM + cs) * 2);
                offA2[i][qm] = (u32)((tk * DCOND + cs) * 2);
            } else if constexpr (MODE == 1) {
                offA1[i][qm] = (u32)((rg * DIM + cs) * 2);
                offA2[i][qm] = (u32)((rg * DCOND + cs) * 2);
            } else {
                offA1[i][qm] = (u32)(((long long)rg * KTOT + cs) * 2);
                offA2[i][qm] = 0;
            }
        }
    }
#pragma unroll
    for (int i = 0; i < SB; ++i) {
        const int g = tid + i * 512;
        int wn, c;
        if constexpr (BN == 256) { wn = g >> 8; c = (g >> 3) & 31; }
        else                     { wn = g >> 7; c = (g >> 3) & 15; }
        const int c16 = g & 7;
        const int cs = (c16 ^ (c & 7)) * 8;
#pragma unroll
        for (int qn = 0; qn < 2; ++qn) {
            const int cbl = (BN == 256) ? (wn * 64 + qn * 32 + c)
                                        : (wn * 32 + qn * 16 + c);
            offB[i][qn] = (u32)(((long long)(n0 + cbl) * KTOT + cs) * 2);
        }
    }

    // LDS read base addresses (as3, byte units). Swizzle XOR folded per kk.
    const u32 AsB = (u32)(size_t)(__attribute__((address_space(3))) u16*)&As[0][0][0];
    const u32 BsB = (u32)(size_t)(__attribute__((address_space(3))) u16*)&Bs[0][0][0];
    const int lrow = lane & 15;
    const int x0 = (((lane >> 4) + 0) ^ (lane & 7)) << 4;
    const int x4 = (((lane >> 4) + 4) ^ (lane & 7)) << 4;
    const u32 aA0 = AsB + (u32)((wmw * 64 + lrow) * 128 + x0);
    const u32 aA1 = AsB + (u32)((wmw * 64 + lrow) * 128 + x4);
    const int bro = (BN == 256 ? wnw * 32 : wnw * 16) + lrow;
    const u32 aB0 = BsB + (u32)(bro * 128 + x0);
    const u32 aB1 = BsB + (u32)(bro * 128 + x4);

    f32x4 acc[8][2 * N9];
#pragma unroll
    for (int m = 0; m < 8; ++m)
#pragma unroll
        for (int n = 0; n < 2 * N9; ++n) { f32x4 zv = {0.f, 0.f, 0.f, 0.f}; acc[m][n] = zv; }

    bf16x8 a[4][2];         // current qm's A frags (single set: reg budget)
    bf16x8 b[2][N9][2];     // both qn halves held

    // Prologue: K0 full -> buf0 (8|6 gloads); K1 {A(1,0),B(1,0),B(1,1)}
    // -> buf1 (A(1,1) staged at first phase I). Wait buf0; barrier.
    STAGE_A(0, 0, 0); STAGE_B(0, 0, 0); STAGE_A(0, 1, 0); STAGE_B(0, 1, 0);
    STAGE_A(1, 0, 1); STAGE_B(1, 0, 1); STAGE_B(1, 1, 1);
    vmwait<VMW>();   // buf0 landed; keep buf1's 2+2*SB in flight
    __builtin_amdgcn_s_barrier();

#pragma unroll 1
    for (int t = 0; t < NKT / 2; ++t) {
        const int k2 = 2 * t;
        const int kA = (k2 + 2 < NKT) ? k2 + 2 : NKT - 1;
        const int kB = (k2 + 3 < NKT) ? k2 + 3 : NKT - 1;
        // -- phase I: buf0 row 0
        STAGE_A(1, 1, k2 + 1);
        READ_A(0, 0); READ_B(0, 0); READ_B(0, 1);
        PH_WAIT(); MFMA_P(0); PH_END();
        // -- phase II: buf0 row 1
        STAGE_A(0, 0, kA); STAGE_B(0, 0, kA); STAGE_B(0, 1, kA);
        READ_A(0, 1);
        PH_WAIT(); MFMA_P(1); PH_END_VM();
        // -- phase III: buf1 row 0
        STAGE_A(0, 1, kA);
        READ_A(1, 0); READ_B(1, 0); READ_B(1, 1);
        PH_WAIT(); MFMA_P(0); PH_END();
        // -- phase IV: buf1 row 1
        STAGE_A(1, 0, kB); STAGE_B(1, 0, kB); STAGE_B(1, 1, kB);
        READ_A(1, 1);
        PH_WAIT(); MFMA_P(1); PH_END_VM();
    }
    // Drain dead prefetch stages before epilogue / endpgm.
    vmwait<0>();

    // Epilogue. C/D layout: col=lane&15, row=(lane>>4)*4+reg (m89/m91).
    u16* Cz = C + (long long)z * cBatch;
#pragma unroll
    for (int m = 0; m < 8; ++m) {
        const int rowb = m0 + wmw * 128 + (m >> 2) * 64 + (m & 3) * 16 + (lane >> 4) * 4;
#pragma unroll
        for (int n = 0; n < 2 * N9; ++n) {
            int col;
            if constexpr (BN == 256)
                col = n0 + wnw * 64 + (n >> 1) * 32 + (n & 1) * 16 + (lane & 15);
            else
                col = n0 + wnw * 32 + n * 16 + (lane & 15);
#pragma unroll
            for (int rr = 0; rr < 4; ++rr) {
                float v = acc[m][n][rr];
                if constexpr (MODE >= 1) v = gelu_f(v);
                Cz[(long long)(rowb + rr) * ldC + col] = f2b(v);
            }
        }
    }
}

// ---------------------------------------------------------------------------
// Combine: out[t] = mask[t]*(xs[t] + 2*(w1*v1*y[e1,p1] + w2*v2*y[e2,p2]))/3
// ---------------------------------------------------------------------------
__global__ __launch_bounds__(256) void moe_combine(
    const u16* __restrict__ xs, const u16* __restrict__ y,
    const float* __restrict__ wbuf, const int* __restrict__ idxbuf,
    const int* __restrict__ slot_of, const void* __restrict__ maskv,
    void* __restrict__ outv, const int* __restrict__ flag)
{
    const int t = blockIdx.x;
    const int c = threadIdx.x * 4;
    const bool isf32 = flag[0] != 0;
    const float mk = isf32 ? ((const float*)maskv)[t] : b2f(((const u16*)maskv)[t]);

    int e1 = idxbuf[2 * t], e2 = idxbuf[2 * t + 1];
    int s1 = slot_of[2 * t], s2 = slot_of[2 * t + 1];
    float w1 = wbuf[2 * t], w2 = wbuf[2 * t + 1];
    float g1 = (s1 < CAP) ? w1 : 0.f;
    float g2 = (s2 < CAP) ? w2 : 0.f;
    int r1 = s1 < CAP ? s1 : CAP - 1;
    int r2 = s2 < CAP ? s2 : CAP - 1;

    uint2 xvv = *(const uint2*)(xs + (long long)t * DIM + c);
    uint2 y1 = *(const uint2*)(y + ((long long)e1 * CAP + r1) * DIM + c);
    uint2 y2 = *(const uint2*)(y + ((long long)e2 * CAP + r2) * DIM + c);
    const u16* xp = (const u16*)&xvv;
    const u16* p1 = (const u16*)&y1;
    const u16* p2 = (const u16*)&y2;

    float o[4];
#pragma unroll
    for (int q = 0; q < 4; ++q) {
        float v = (b2f(xp[q]) + 2.f * (g1 * b2f(p1[q]) + g2 * b2f(p2[q]))) * mk * (1.f / 3.f);
        o[q] = (v == v) ? v : 0.f;
    }
    if (isf32) {
        float4 o4 = {o[0], o[1], o[2], o[3]};
        *(float4*)((float*)outv + (long long)t * DIM + c) = o4;
    } else {
        __align__(8) u16 ov[4];
#pragma unroll
        for (int q = 0; q < 4; ++q) ov[q] = f2b(o[q]);
        *(uint2*)((u16*)outv + (long long)t * DIM + c) = *(const uint2*)ov;
    }
}

// ---------------------------------------------------------------------------
extern "C" void kernel_launch(void* const* d_in, const int* in_sizes, int n_in,
                              void* d_out, int out_size, void* d_ws, size_t ws_size,
                              hipStream_t stream)
{
    const void* x    = d_in[0];
    const void* cond = d_in[1];
    const void* mask = d_in[2];
    const void* Wr   = d_in[3];
    const void* W1s  = d_in[4];
    const void* W2s  = d_in[5];
    const void* W1e  = d_in[6];
    const void* W2e  = d_in[7];

    const int KIN = DIM + DCOND;   // 1280
    const int EGX = 3;             // max experts per group ({3,3,2} grouping)

    // Workspace carve (~223 MB; round-1/2 proved >=237 MB mapped).
    char* p = (char*)d_ws;
    u16* W1sT   = (u16*)p; p += (long long)DFF * KIN * 2;          // 10.5 MB
    u16* W2sT   = (u16*)p; p += (long long)DIM * DFF * 2;          //  8.4 MB
    u16* W1eT   = (u16*)p; p += (long long)EGX * DFF * KIN * 2;    // 31.5 MB
    u16* W2eT   = (u16*)p; p += (long long)EGX * DIM * DFF * 2;    // 25.2 MB
    u16* h      = (u16*)p; p += (long long)T_TOK * DFF * 2;        // 67.1 MB (>= EGX*CAP*DFF)
    u16* xs     = (u16*)p; p += (long long)T_TOK * DIM * 2;        // 16.8 MB
    u16* y      = (u16*)p; p += (long long)NEXP * CAP * DIM * 2;   // 41.9 MB
    u16* xb     = (u16*)p; p += (long long)T_TOK * DIM * 2;        // 16.8 MB
    u16* cb     = (u16*)p; p += (long long)T_TOK * DCOND * 2;      //  4.2 MB
    float* wbuf = (float*)p; p += T_TOK * 2 * sizeof(float);
    int* idxbuf = (int*)p;   p += T_TOK * 2 * sizeof(int);
    int* slot_of = (int*)p;  p += T_TOK * 2 * sizeof(int);
    int* token_of = (int*)p; p += NEXP * CAP * sizeof(int);
    int* rows_e = (int*)p;   p += 256;
    int* flag   = (int*)p;   p += 256;
    (void)ws_size; (void)in_sizes; (void)n_in; (void)out_size;

    dim3 b256(256);
    dim3 b512(512);

    moe_probe<<<dim3(1), dim3(64), 0, stream>>>((const u16*)x, flag);

    // Normalize activations to bf16 once (GEMMs become single-path DMA).
    moe_cvt<<<dim3(T_TOK * DIM / (256 * 8)), b256, 0, stream>>>(x, xb, flag);
    moe_cvt<<<dim3(T_TOK * DCOND / (256 * 8)), b256, 0, stream>>>(cond, cb, flag);

    moe_router<<<dim3(T_TOK / 4), b256, 0, stream>>>(x, Wr, flag, wbuf, idxbuf);
    moe_bins<<<dim3(1), dim3(64), 0, stream>>>(idxbuf, slot_of, token_of, rows_e);

    moe_transpose<<<dim3(DFF / 64, KIN / 64, 1), b256, 0, stream>>>(
        W1s, W1sT, flag, KIN, DFF, 0, 0, 0);
    moe_transpose<<<dim3(DIM / 64, DFF / 64, 1), b256, 0, stream>>>(
        W2s, W2sT, flag, DFF, DIM, 0, 0, 0);

    // Shared expert: h = gelu([xb|cb] @ W1s); xs = h @ W2s.
    moe_gemm_4p<1, 1280, 256><<<dim3(DFF / 256, T_TOK / 256, 1), b512, 0, stream>>>(
        xb, cb, W1sT, h, nullptr, nullptr, DFF, 0, 0, 0);
    moe_gemm_4p<0, 4096, 128><<<dim3(DIM / 128, T_TOK / 256, 1), b512, 0, stream>>>(
        h, nullptr, W2sT, xs, nullptr, nullptr, DIM, 0, 0, 0);

    // Routed experts, groups of {3,3,2} (z-batched).
    const int gsz[3] = {3, 3, 2};
    int gb = 0;
    for (int gi = 0; gi < 3; ++gi) {
        const int eg = gsz[gi];
        moe_transpose<<<dim3(DFF / 64, KIN / 64, eg), b256, 0, stream>>>(
            W1e, W1eT, flag, KIN, DFF, gb,
            (long long)KIN * DFF, (long long)DFF * KIN);
        moe_transpose<<<dim3(DIM / 64, DFF / 64, eg), b256, 0, stream>>>(
            W2e, W2eT, flag, DFF, DIM, gb,
            (long long)DFF * DIM, (long long)DIM * DFF);

        moe_gemm_4p<2, 1280, 256><<<dim3(DFF / 256, CAP / 256, eg), b512, 0, stream>>>(
            xb, cb, W1eT, h, token_of + (long long)gb * CAP, rows_e + gb,
            DFF, 0, (long long)DFF * KIN, (long long)CAP * DFF);
        moe_gemm_4p<0, 4096, 128><<<dim3(DIM / 128, CAP / 256, eg), b512, 0, stream>>>(
            h, nullptr, W2eT, y + (long long)gb * CAP * DIM, nullptr, rows_e + gb,
            DIM, (long long)CAP * DFF, (long long)DIM * DFF, (long long)CAP * DIM);
        gb += eg;
    }

    moe_combine<<<dim3(T_TOK), b256, 0, stream>>>(xs, y, wbuf, idxbuf, slot_of, mask, d_out, flag);
}